// Round 1
// baseline (777.266 us; speedup 1.0000x reference)
//
#include <hip/hip_runtime.h>

#define DIM 64
#define EPS 1e-12f

// ---- float <-> order-preserving unsigned (for atomicMax on float) ----
__device__ __forceinline__ unsigned f2sortable(float f) {
    unsigned u = __float_as_uint(f);
    return (u & 0x80000000u) ? ~u : (u | 0x80000000u);
}
__device__ __forceinline__ float sortable2f(unsigned u) {
    u = (u & 0x80000000u) ? (u & 0x7FFFFFFFu) : ~u;
    return __uint_as_float(u);
}

// init: out = ent, x = ent   (vectorized float4 copy)
__global__ void init_kernel(const float4* __restrict__ ent4,
                            float4* __restrict__ out4,
                            float4* __restrict__ x4, int n4) {
    int i = blockIdx.x * blockDim.x + threadIdx.x;
    if (i >= n4) return;
    float4 v = ent4[i];
    out4[i] = v;
    x4[i]   = v;
}

// one wave (64 lanes) per edge: kg_score + segment max
__global__ void score_kernel(const float* __restrict__ ent,
                             const float* __restrict__ relemb,
                             const int* __restrict__ head,
                             const int* __restrict__ tail,
                             const int* __restrict__ etype,
                             float* __restrict__ kg,
                             unsigned* __restrict__ segmax, int E) {
    int wid  = (blockIdx.x * blockDim.x + threadIdx.x) >> 6;
    int lane = threadIdx.x & 63;
    if (wid >= E) return;
    int h = head[wid], t = tail[wid], r = etype[wid] - 1;
    float v = ent[h * DIM + lane] * relemb[r * DIM + lane] * ent[t * DIM + lane];
    #pragma unroll
    for (int off = 32; off; off >>= 1) v += __shfl_xor(v, off, 64);
    if (lane == 0) {
        kg[wid] = v;
        atomicMax(&segmax[h], f2sortable(v));
    }
}

// one thread per edge: ex = exp(kg - max), segment sum
__global__ void ex_kernel(const int* __restrict__ head,
                          const float* __restrict__ kg,
                          const unsigned* __restrict__ segmax,
                          float* __restrict__ ex,
                          float* __restrict__ segsum, int E) {
    int e = blockIdx.x * blockDim.x + threadIdx.x;
    if (e >= E) return;
    int h = head[e];
    float m  = sortable2f(segmax[h]);
    float v  = __expf(kg[e] - m);
    ex[e] = v;
    atomicAdd(&segsum[h], v);
}

// one thread per edge: score = ex / segsum[head]
__global__ void div_kernel(const int* __restrict__ head,
                           float* __restrict__ ex,
                           const float* __restrict__ segsum, int E) {
    int e = blockIdx.x * blockDim.x + threadIdx.x;
    if (e >= E) return;
    ex[e] = ex[e] / segsum[head[e]];
}

// one wave per edge: agg[head] += score * rel * x[tail]
__global__ void agg_kernel(const float* __restrict__ relemb,
                           const int* __restrict__ head,
                           const int* __restrict__ tail,
                           const int* __restrict__ etype,
                           const float* __restrict__ score,
                           const float* __restrict__ x,
                           float* __restrict__ agg, int E) {
    int wid  = (blockIdx.x * blockDim.x + threadIdx.x) >> 6;
    int lane = threadIdx.x & 63;
    if (wid >= E) return;
    int h = head[wid], t = tail[wid], r = etype[wid] - 1;
    float c = score[wid];
    float v = c * relemb[r * DIM + lane] * x[t * DIM + lane];
    atomicAdd(&agg[h * DIM + lane], v);
}

// one wave per node: x = agg/max(||agg||,eps); out += x
__global__ void norm_kernel(const float* __restrict__ agg,
                            float* __restrict__ x,
                            float* __restrict__ out, int N) {
    int wid  = (blockIdx.x * blockDim.x + threadIdx.x) >> 6;
    int lane = threadIdx.x & 63;
    if (wid >= N) return;
    float a = agg[wid * DIM + lane];
    float s = a * a;
    #pragma unroll
    for (int off = 32; off; off >>= 1) s += __shfl_xor(s, off, 64);
    float nrm = sqrtf(s);
    float xn = a / fmaxf(nrm, EPS);
    x[wid * DIM + lane]    = xn;
    out[wid * DIM + lane] += xn;
}

extern "C" void kernel_launch(void* const* d_in, const int* in_sizes, int n_in,
                              void* d_out, int out_size, void* d_ws, size_t ws_size,
                              hipStream_t stream) {
    const float* ent    = (const float*)d_in[0];
    const float* relemb = (const float*)d_in[1];
    const int*   eidx   = (const int*)d_in[2];
    const int*   etype  = (const int*)d_in[3];
    float* out = (float*)d_out;

    const int N = in_sizes[0] / DIM;       // 50000
    const int E = in_sizes[3];             // 800000
    const int* head = eidx;
    const int* tail = eidx + E;

    // workspace layout (bytes, 256-aligned)
    char* ws = (char*)d_ws;
    size_t off = 0;
    auto alloc = [&](size_t bytes) {
        char* p = ws + off;
        off += (bytes + 255) & ~size_t(255);
        return p;
    };
    float*    kg     = (float*)alloc((size_t)E * 4);
    float*    ex     = (float*)alloc((size_t)E * 4);
    unsigned* segmax = (unsigned*)alloc((size_t)N * 4);
    float*    segsum = (float*)alloc((size_t)N * 4);
    float*    x      = (float*)alloc((size_t)N * DIM * 4);
    float*    agg    = (float*)alloc((size_t)N * DIM * 4);
    (void)ws_size;

    hipMemsetAsync(segmax, 0, (size_t)N * 4, stream);   // sortable(-inf) == 0
    hipMemsetAsync(segsum, 0, (size_t)N * 4, stream);

    // init out = x = ent
    {
        int n4 = N * DIM / 4;
        init_kernel<<<(n4 + 255) / 256, 256, 0, stream>>>(
            (const float4*)ent, (float4*)out, (float4*)x, n4);
    }

    // softmax over head segments
    {
        int waveBlocks = (E + 3) / 4;  // 4 waves / 256-thread block
        score_kernel<<<waveBlocks, 256, 0, stream>>>(ent, relemb, head, tail, etype,
                                                     kg, segmax, E);
        ex_kernel<<<(E + 255) / 256, 256, 0, stream>>>(head, kg, segmax, ex, segsum, E);
        div_kernel<<<(E + 255) / 256, 256, 0, stream>>>(head, ex, segsum, E);
    }

    // 3 hops
    for (int hop = 0; hop < 3; ++hop) {
        hipMemsetAsync(agg, 0, (size_t)N * DIM * 4, stream);
        int waveBlocks = (E + 3) / 4;
        agg_kernel<<<waveBlocks, 256, 0, stream>>>(relemb, head, tail, etype,
                                                   ex, x, agg, E);
        int nodeBlocks = (N + 3) / 4;
        norm_kernel<<<nodeBlocks, 256, 0, stream>>>(agg, x, out, N);
    }
}

// Round 2
// 577.830 us; speedup vs baseline: 1.3451x; 1.3451x over previous
//
#include <hip/hip_runtime.h>

#define DIM 64
#define EPS 1e-12f
#define TMASK 0xFFFFF   // tail in low 20 bits, relation idx in high bits

__device__ __forceinline__ float wave_sum(float v) {
    #pragma unroll
    for (int off = 32; off; off >>= 1) v += __shfl_xor(v, off, 64);
    return v;
}

// out = ent, x0 = ent
__global__ void init_kernel(const float4* __restrict__ ent4,
                            float4* __restrict__ out4,
                            float4* __restrict__ x4, int n4) {
    int i = blockIdx.x * blockDim.x + threadIdx.x;
    if (i >= n4) return;
    float4 v = ent4[i];
    out4[i] = v;
    x4[i]   = v;
}

__global__ void hist_kernel(const int* __restrict__ head, int* __restrict__ counts, int E) {
    int e = blockIdx.x * blockDim.x + threadIdx.x;
    if (e < E) atomicAdd(&counts[head[e]], 1);
}

// single-block exclusive scan: counts[0..N) -> row_ptr[0..N], cursor copy
__global__ void scan_kernel(const int* __restrict__ counts,
                            int* __restrict__ row_ptr,
                            int* __restrict__ cursor, int N) {
    const int T = 1024;
    int tid = threadIdx.x;
    int chunk = (N + T - 1) / T;
    int beg = tid * chunk;
    int end = min(beg + chunk, N);
    int s = 0;
    for (int i = beg; i < end; ++i) s += counts[i];
    int lane = tid & 63, wid = tid >> 6;
    int v = s;
    #pragma unroll
    for (int off = 1; off < 64; off <<= 1) {
        int t = __shfl_up(v, off, 64);
        if (lane >= off) v += t;
    }
    __shared__ int wsum[16];
    __shared__ int wbase[16];
    if (lane == 63) wsum[wid] = v;
    __syncthreads();
    if (tid == 0) {
        int a = 0;
        for (int i = 0; i < 16; ++i) { wbase[i] = a; a += wsum[i]; }
    }
    __syncthreads();
    int run = wbase[wid] + v - s;   // exclusive prefix of this thread's chunk
    for (int i = beg; i < end; ++i) {
        row_ptr[i] = run;
        cursor[i]  = run;
        run += counts[i];
    }
    if (beg < N && end == N) row_ptr[N] = run;   // total
}

__global__ void scatter_kernel(const int* __restrict__ head,
                               const int* __restrict__ tail,
                               const int* __restrict__ etype,
                               int* __restrict__ cursor,
                               int* __restrict__ packed, int E) {
    int e = blockIdx.x * blockDim.x + threadIdx.x;
    if (e >= E) return;
    int h = head[e];
    int pos = atomicAdd(&cursor[h], 1);
    packed[pos] = (tail[e] & TMASK) | ((etype[e] - 1) << 20);
}

// wave per node: kg scores + stable segment softmax, all in one kernel
__global__ void score_softmax_kernel(const float* __restrict__ ent,
                                     const float* __restrict__ relemb,
                                     const int* __restrict__ row_ptr,
                                     const int* __restrict__ packed,
                                     float* __restrict__ score, int N, int R) {
    __shared__ float srel[2048];            // up to 32 relations x 64
    for (int i = threadIdx.x; i < R * DIM; i += blockDim.x) srel[i] = relemb[i];
    __syncthreads();
    int w    = (blockIdx.x * blockDim.x + threadIdx.x) >> 6;
    int lane = threadIdx.x & 63;
    if (w >= N) return;
    int beg = row_ptr[w], end = row_ptr[w + 1];
    if (beg == end) return;
    float eh = ent[w * DIM + lane];
    float m = -3.4e38f;
    for (int i = beg; i < end; ++i) {
        int p = packed[i];
        float v = eh * srel[(p >> 20) * DIM + lane] * ent[(p & TMASK) * DIM + lane];
        v = wave_sum(v);                         // all lanes hold the dot product
        if (lane == ((i - beg) & 63)) score[i] = v;   // owner-lane store (same lane re-reads below)
        m = fmaxf(m, v);
    }
    float s = 0.f;
    for (int i = beg + lane; i < end; i += 64) {
        float v = __expf(score[i] - m);
        score[i] = v;
        s += v;
    }
    s = wave_sum(s);
    float inv = 1.0f / s;
    for (int i = beg + lane; i < end; i += 64) score[i] *= inv;
}

// wave per node: agg = sum(score * rel * x_old[tail]); normalize; out += ; write x_new
__global__ void hop_kernel(const float* __restrict__ relemb,
                           const int* __restrict__ row_ptr,
                           const int* __restrict__ packed,
                           const float* __restrict__ score,
                           const float* __restrict__ x_old,
                           float* __restrict__ x_new,
                           float* __restrict__ out, int N, int R) {
    __shared__ float srel[2048];
    for (int i = threadIdx.x; i < R * DIM; i += blockDim.x) srel[i] = relemb[i];
    __syncthreads();
    int w    = (blockIdx.x * blockDim.x + threadIdx.x) >> 6;
    int lane = threadIdx.x & 63;
    if (w >= N) return;
    int beg = row_ptr[w], end = row_ptr[w + 1];
    float acc = 0.f;
    for (int i = beg; i < end; ++i) {
        int p = packed[i];
        acc += score[i] * srel[(p >> 20) * DIM + lane] * x_old[(p & TMASK) * DIM + lane];
    }
    float s = wave_sum(acc * acc);
    float xn = acc / fmaxf(sqrtf(s), EPS);
    x_new[w * DIM + lane] = xn;
    out[w * DIM + lane]  += xn;
}

extern "C" void kernel_launch(void* const* d_in, const int* in_sizes, int n_in,
                              void* d_out, int out_size, void* d_ws, size_t ws_size,
                              hipStream_t stream) {
    const float* ent    = (const float*)d_in[0];
    const float* relemb = (const float*)d_in[1];
    const int*   eidx   = (const int*)d_in[2];
    const int*   etype  = (const int*)d_in[3];
    float* out = (float*)d_out;

    const int N = in_sizes[0] / DIM;   // 50000
    const int R = in_sizes[1] / DIM;   // 20
    const int E = in_sizes[3];         // 800000
    const int* head = eidx;
    const int* tail = eidx + E;

    char* ws = (char*)d_ws;
    size_t off = 0;
    auto alloc = [&](size_t bytes) {
        char* p = ws + off;
        off += (bytes + 255) & ~size_t(255);
        return p;
    };
    int*   counts  = (int*)alloc((size_t)N * 4);
    int*   row_ptr = (int*)alloc((size_t)(N + 1) * 4);
    int*   cursor  = (int*)alloc((size_t)N * 4);
    int*   packed  = (int*)alloc((size_t)E * 4);
    float* score   = (float*)alloc((size_t)E * 4);
    float* x0      = (float*)alloc((size_t)N * DIM * 4);
    float* x1      = (float*)alloc((size_t)N * DIM * 4);
    (void)ws_size;

    hipMemsetAsync(counts, 0, (size_t)N * 4, stream);

    // init out = x0 = ent
    {
        int n4 = N * DIM / 4;
        init_kernel<<<(n4 + 255) / 256, 256, 0, stream>>>(
            (const float4*)ent, (float4*)out, (float4*)x0, n4);
    }

    // CSR by head
    hist_kernel<<<(E + 255) / 256, 256, 0, stream>>>(head, counts, E);
    scan_kernel<<<1, 1024, 0, stream>>>(counts, row_ptr, cursor, N);
    scatter_kernel<<<(E + 255) / 256, 256, 0, stream>>>(head, tail, etype, cursor, packed, E);

    // per-node score + softmax
    int nodeBlocks = (N + 3) / 4;   // 4 waves / block
    score_softmax_kernel<<<nodeBlocks, 256, 0, stream>>>(ent, relemb, row_ptr, packed,
                                                         score, N, R);

    // 3 hops, ping-pong x
    hop_kernel<<<nodeBlocks, 256, 0, stream>>>(relemb, row_ptr, packed, score, x0, x1, out, N, R);
    hop_kernel<<<nodeBlocks, 256, 0, stream>>>(relemb, row_ptr, packed, score, x1, x0, out, N, R);
    hop_kernel<<<nodeBlocks, 256, 0, stream>>>(relemb, row_ptr, packed, score, x0, x1, out, N, R);
}